// Round 16
// baseline (318.542 us; speedup 1.0000x reference)
//
#include <hip/hip_runtime.h>
#include <math.h>

// Problem constants (B,L,E,H,D) = (8,1024,1024,16,64)
constexpr int Bc = 8;
constexpr int Lc = 1024;
constexpr int Ec = 1024;
constexpr int Hc = 16;
constexpr int Dc = 64;
constexpr float EPSc = 1e-5f;

// ---- fp16 types ----
typedef _Float16 f16;
typedef f16 half8 __attribute__((ext_vector_type(8)));
typedef float floatx4 __attribute__((ext_vector_type(4)));

// async global->LDS 16B
static __device__ inline void gload_lds16(const f16* g, f16* l) {
    __builtin_amdgcn_global_load_lds(
        (const __attribute__((address_space(1))) void*)g,
        (__attribute__((address_space(3))) void*)l, 16, 0, 0);
}

// ---------------------------------------------------------------------------
// Fused fp32 -> fp16 conversion for x, w_qkv, w_out in ONE launch. (UNCHANGED)
// ---------------------------------------------------------------------------
static __device__ inline void cvt_body(const float* __restrict__ src,
                                       f16* __restrict__ dst, int n8,
                                       int blk, int nblk) {
    int i = blk * 256 + threadIdx.x;
    const int stride = nblk * 256;
    for (; i < n8; i += stride) {
        float4 a = *(const float4*)(src + (size_t)i * 8);
        float4 b = *(const float4*)(src + (size_t)i * 8 + 4);
        half8 p;
        p[0] = (f16)a.x; p[1] = (f16)a.y; p[2] = (f16)a.z; p[3] = (f16)a.w;
        p[4] = (f16)b.x; p[5] = (f16)b.y; p[6] = (f16)b.z; p[7] = (f16)b.w;
        *(half8*)(dst + (size_t)i * 8) = p;
    }
}

__global__ __launch_bounds__(256)
void cvt3_kernel(const float* __restrict__ x, const float* __restrict__ wq,
                 const float* __restrict__ wo, f16* __restrict__ xh,
                 f16* __restrict__ wqh, f16* __restrict__ woh) {
    const int b = blockIdx.x;
    if (b < 2048)       cvt_body(x,  xh,  (Bc * Lc * Ec) / 8, b, 2048);
    else if (b < 3584)  cvt_body(wq, wqh, (3 * Ec * Ec) / 8, b - 2048, 1536);
    else                cvt_body(wo, woh, (Ec * Ec) / 8, b - 3584, 512);
}

// ---------------------------------------------------------------------------
// GEMM (R11 core, UNCHANGED): MFMA fp16 + global_load_lds, KT=64,
// row-major LDS + chunk-XOR.  fp32-output path optionally fuses
// residual add (h = acc+bias+resid; commutative -> bit-identical) and
// LayerNorm partial sums (row sum/sumsq of h via shfl-reduce + atomics).
// Atomic count: 2/row/wave-half = 262k over 16k addresses (pool-proven class).
// ---------------------------------------------------------------------------
__global__ __launch_bounds__(256)
void gemm_nt_h(const f16* __restrict__ A, const f16* __restrict__ Bm,
               const float* __restrict__ bias, const float* __restrict__ resid,
               float* __restrict__ spart, float* __restrict__ Cf,
               f16* __restrict__ Ch, int M, int N, int K) {
    constexpr int TILE = 128;
    constexpr int KT = 64;
    constexpr int RSs = 64;                        // row stride in f16
    __shared__ __align__(16) f16 As[TILE * RSs];   // 16 KB
    __shared__ __align__(16) f16 Bs[TILE * RSs];   // 16 KB

    const int tid = threadIdx.x;
    const int bm = blockIdx.x * TILE;
    const int bn = blockIdx.y * TILE;

    const int wave = tid >> 6;
    const int lane = tid & 63;
    const int wm = (wave >> 1) * 64;
    const int wn = (wave & 1) * 64;
    const int r16 = lane & 15;
    const int kg = lane >> 4;
    const int kx = r16 & 7;                        // read-side XOR key (= row&7)

    floatx4 acc[4][4];
#pragma unroll
    for (int i = 0; i < 4; ++i)
#pragma unroll
        for (int j = 0; j < 4; ++j) acc[i][j] = (floatx4){0.f, 0.f, 0.f, 0.f};

    const int rbase = tid >> 3;                    // 0..31
    const int kcg = (tid & 7) ^ (rbase & 7);       // pre-swizzled global k-chunk
    const f16* apt = A + (size_t)(bm + rbase) * K + kcg * 8;
    const f16* bpt = Bm + (size_t)(bn + rbase) * K + kcg * 8;
    f16* asl = As + tid * 8;
    f16* bsl = Bs + tid * 8;

    for (int k0 = 0; k0 < K; k0 += KT) {
        __syncthreads();                           // prior ds_reads complete
#pragma unroll
        for (int q = 0; q < 4; ++q) {
            gload_lds16(apt + (size_t)(q * 32) * K + k0, asl + q * 2048);
            gload_lds16(bpt + (size_t)(q * 32) * K + k0, bsl + q * 2048);
        }
        __syncthreads();                           // vmcnt(0) drained by compiler

#pragma unroll
        for (int ks = 0; ks < 2; ++ks) {
            const int kslot = ((ks * 4 + kg) ^ kx) * 8;
            half8 af[4], bf[4];
#pragma unroll
            for (int i = 0; i < 4; ++i)
                af[i] = *(const half8*)&As[(wm + 16 * i + r16) * RSs + kslot];
#pragma unroll
            for (int j = 0; j < 4; ++j)
                bf[j] = *(const half8*)&Bs[(wn + 16 * j + r16) * RSs + kslot];
#pragma unroll
            for (int i = 0; i < 4; ++i)
#pragma unroll
                for (int j = 0; j < 4; ++j)
                    acc[i][j] = __builtin_amdgcn_mfma_f32_16x16x32_f16(af[i], bf[j], acc[i][j], 0, 0, 0);
        }
    }

    if (Ch) {
#pragma unroll
        for (int j = 0; j < 4; ++j) {
            const int col = bn + wn + 16 * j + r16;
            const float bv = bias[col];
#pragma unroll
            for (int i = 0; i < 4; ++i) {
                const int row0e = bm + wm + 16 * i + kg * 4;
#pragma unroll
                for (int r = 0; r < 4; ++r)
                    Ch[(size_t)(row0e + r) * N + col] = (f16)(acc[i][j][r] + bv);
            }
        }
    } else {
        float rsum[4][4], rsq[4][4];
#pragma unroll
        for (int i = 0; i < 4; ++i)
#pragma unroll
            for (int r = 0; r < 4; ++r) { rsum[i][r] = 0.f; rsq[i][r] = 0.f; }
#pragma unroll
        for (int j = 0; j < 4; ++j) {
            const int col = bn + wn + 16 * j + r16;
            const float bv = bias[col];
#pragma unroll
            for (int i = 0; i < 4; ++i) {
                const int row0e = bm + wm + 16 * i + kg * 4;
#pragma unroll
                for (int r = 0; r < 4; ++r) {
                    const size_t idx = (size_t)(row0e + r) * N + col;
                    float v = acc[i][j][r] + bv;
                    if (resid) v += resid[idx];
                    Cf[idx] = v;
                    rsum[i][r] += v;
                    rsq[i][r] += v * v;
                }
            }
        }
        if (spart) {
#pragma unroll
            for (int i = 0; i < 4; ++i)
#pragma unroll
                for (int r = 0; r < 4; ++r) {
                    float s = rsum[i][r], q = rsq[i][r];
                    s += __shfl_xor(s, 1); s += __shfl_xor(s, 2);
                    s += __shfl_xor(s, 4); s += __shfl_xor(s, 8);
                    q += __shfl_xor(q, 1); q += __shfl_xor(q, 2);
                    q += __shfl_xor(q, 4); q += __shfl_xor(q, 8);
                    if (r16 == 0) {
                        const int row = bm + wm + 16 * i + kg * 4 + r;
                        atomicAdd(&spart[2 * row], s);
                        atomicAdd(&spart[2 * row + 1], q);
                    }
                }
        }
    }
}

// ---------------------------------------------------------------------------
// Attention v9 (UNCHANGED from R15, proven 116.8 us): T14 prefetch +
// XCD-locality grid (h, qt, b).
// ---------------------------------------------------------------------------
constexpr int AQT = 128;
constexpr int AKT = 128;
constexpr int ANT = Lc / AKT;   // 8 tiles
constexpr int AKP = 72;      // f16 stride [row][d]
constexpr int AWP = 136;     // f16 stride WS [q][k]
constexpr int AVP = 136;     // f16 stride Vt [d][k]

constexpr int AQ_OFF  = 0;                   // Kq 128*72 f16 = 4608 w
constexpr int AKV_OFF = 4608;                // Kt 4608 w | Vt 64*136 f16 = 4352 w
constexpr int AW_OFF  = AKV_OFF + 4608;      // WS 128*136 f16 = 8704 w
constexpr int ARS_OFF = AW_OFF + 8704;       // RS fp32 [128]
constexpr int ACOL_OFF = ARS_OFF + 128;      // COL fp32 [1024]
constexpr int ASMEM   = ACOL_OFF + 1024;     // 19072 w = 76288 B

__global__ __launch_bounds__(256, 2)
void attn_kernel(const f16* __restrict__ qkv, f16* __restrict__ ctx,
                 float* __restrict__ avg_out) {
    __shared__ __align__(16) float smemf[ASMEM];
    f16* Kq = (f16*)(smemf + AQ_OFF);    // [q][d] (scaled by 0.125)
    f16* Kt = (f16*)(smemf + AKV_OFF);   // [k][d]
    f16* Vt = (f16*)(smemf + AKV_OFF);   // [d][k] (union)
    f16* WS = (f16*)(smemf + AW_OFF);    // [q][k]
    float* RS  = smemf + ARS_OFF;
    float* COL = smemf + ACOL_OFF;

    const int tid = threadIdx.x;
    const int h = blockIdx.x, qt = blockIdx.y, b = blockIdx.z;   // XCD = h&7
    const int l0 = qt * AQT;
    const size_t rowstride = 3 * Ec;     // f16 units
    const f16* base = qkv + (size_t)b * Lc * rowstride + (size_t)h * Dc;

    const int wave = tid >> 6, lane = tid & 63;
    const int r16 = lane & 15, kg = lane >> 4;
    const int wm = (wave >> 1) * 64;
    const int wn = (wave & 1) * 64;

    if (tid < 128) RS[tid] = 0.f;
#pragma unroll
    for (int t = 0; t < 4; ++t) COL[t * 256 + tid] = 0.f;

    const int srow = tid >> 1;
    const int sh = (tid & 1) * 32;       // f16 offset 0 or 32

    // stage Q (x 0.125, exact in f16)
    {
        const f16* src = base + (size_t)(l0 + srow) * rowstride + sh;
        f16* dst = Kq + srow * AKP + sh;
#pragma unroll
        for (int jj = 0; jj < 4; ++jj) {
            half8 p = *(const half8*)(src + jj * 8);
#pragma unroll
            for (int e = 0; e < 8; ++e) p[e] = p[e] * (f16)0.125f;
            *(half8*)(dst + jj * 8) = p;
        }
    }

    const f16* kstage = base + (size_t)srow * rowstride + Ec + sh;   // tile-0 K src
    half8 kreg[4];
#pragma unroll
    for (int jj = 0; jj < 4; ++jj) kreg[jj] = *(const half8*)(kstage + jj * 8);

    // ================= sweep 1: row sums of exp(scores) =================
    float rs[4][4];
#pragma unroll
    for (int i = 0; i < 4; ++i)
#pragma unroll
        for (int r = 0; r < 4; ++r) rs[i][r] = 0.f;

    for (int kt = 0; kt < ANT; ++kt) {
        __syncthreads();
        {   // write prefetched K tile to LDS
            f16* dst = Kt + srow * AKP + sh;
#pragma unroll
            for (int jj = 0; jj < 4; ++jj)
                *(half8*)(dst + jj * 8) = kreg[jj];
        }
        if (kt + 1 < ANT) {   // prefetch next K tile (hides under compute)
            const f16* src = kstage + (size_t)((kt + 1) * AKT) * rowstride;
#pragma unroll
            for (int jj = 0; jj < 4; ++jj) kreg[jj] = *(const half8*)(src + jj * 8);
        }
        __syncthreads();

        floatx4 s[4][4];
#pragma unroll
        for (int i = 0; i < 4; ++i)
#pragma unroll
            for (int j = 0; j < 4; ++j) s[i][j] = (floatx4){0.f, 0.f, 0.f, 0.f};
#pragma unroll
        for (int ks = 0; ks < 2; ++ks) {
            half8 af[4], bf[4];
#pragma unroll
            for (int i = 0; i < 4; ++i)
                af[i] = *(const half8*)&Kq[(wm + 16 * i + r16) * AKP + ks * 32 + kg * 8];
#pragma unroll
            for (int j = 0; j < 4; ++j)
                bf[j] = *(const half8*)&Kt[(wn + 16 * j + r16) * AKP + ks * 32 + kg * 8];
#pragma unroll
            for (int i = 0; i < 4; ++i)
#pragma unroll
                for (int j = 0; j < 4; ++j)
                    s[i][j] = __builtin_amdgcn_mfma_f32_16x16x32_f16(af[i], bf[j], s[i][j], 0, 0, 0);
        }
#pragma unroll
        for (int i = 0; i < 4; ++i)
#pragma unroll
            for (int r = 0; r < 4; ++r)
                rs[i][r] += __expf(s[i][0][r]) + __expf(s[i][1][r]) +
                            __expf(s[i][2][r]) + __expf(s[i][3][r]);
    }

    // reload K tile 0 for sweep 2 (overlaps the RS reduction below)
#pragma unroll
    for (int jj = 0; jj < 4; ++jj) kreg[jj] = *(const half8*)(kstage + jj * 8);

#pragma unroll
    for (int i = 0; i < 4; ++i)
#pragma unroll
        for (int r = 0; r < 4; ++r) {
            float v = rs[i][r];
            v += __shfl_xor(v, 1); v += __shfl_xor(v, 2);
            v += __shfl_xor(v, 4); v += __shfl_xor(v, 8);
            rs[i][r] = v;
        }
    if (r16 == 0) {
#pragma unroll
        for (int i = 0; i < 4; ++i)
#pragma unroll
            for (int r = 0; r < 4; ++r)
                atomicAdd(&RS[wm + 16 * i + 4 * kg + r], rs[i][r]);
    }
    __syncthreads();
    if (tid < 128) RS[tid] = 1.0f / RS[tid];
    __syncthreads();

    float rinv[4][4];
#pragma unroll
    for (int i = 0; i < 4; ++i)
#pragma unroll
        for (int r = 0; r < 4; ++r) rinv[i][r] = RS[wm + 16 * i + 4 * kg + r];

    // ================= sweep 2: w -> WS, col sums, PV =================
    floatx4 cacc[2][4];
#pragma unroll
    for (int p = 0; p < 2; ++p)
#pragma unroll
        for (int j = 0; j < 4; ++j) cacc[p][j] = (floatx4){0.f, 0.f, 0.f, 0.f};
    const int qb = wave * 32;

    for (int kt = 0; kt < ANT; ++kt) {
        __syncthreads();   // prev PV reads of WS/Vt done
        {   // write prefetched K tile to LDS
            f16* dst = Kt + srow * AKP + sh;
#pragma unroll
            for (int jj = 0; jj < 4; ++jj)
                *(half8*)(dst + jj * 8) = kreg[jj];
        }
        // issue THIS tile's V loads (latency hides under QK^T)
        half8 vreg[4];
        {
            const f16* src = base + (size_t)(kt * AKT + srow) * rowstride + 2 * Ec + sh;
#pragma unroll
            for (int jj = 0; jj < 4; ++jj) vreg[jj] = *(const half8*)(src + jj * 8);
        }
        if (kt + 1 < ANT) {   // prefetch next K tile
            const f16* src = kstage + (size_t)((kt + 1) * AKT) * rowstride;
#pragma unroll
            for (int jj = 0; jj < 4; ++jj) kreg[jj] = *(const half8*)(src + jj * 8);
        }
        __syncthreads();

        floatx4 s[4][4];
#pragma unroll
        for (int i = 0; i < 4; ++i)
#pragma unroll
            for (int j = 0; j < 4; ++j) s[i][j] = (floatx4){0.f, 0.f, 0.f, 0.f};
#pragma unroll
        for (int ks = 0; ks < 2; ++ks) {
            half8 af[4], bf[4];
#pragma unroll
            for (int i = 0; i < 4; ++i)
                af[i] = *(const half8*)&Kq[(wm + 16 * i + r16) * AKP + ks * 32 + kg * 8];
#pragma unroll
            for (int j = 0; j < 4; ++j)
                bf[j] = *(const half8*)&Kt[(wn + 16 * j + r16) * AKP + ks * 32 + kg * 8];
#pragma unroll
            for (int i = 0; i < 4; ++i)
#pragma unroll
                for (int j = 0; j < 4; ++j)
                    s[i][j] = __builtin_amdgcn_mfma_f32_16x16x32_f16(af[i], bf[j], s[i][j], 0, 0, 0);
        }

        float cs[4] = {0.f, 0.f, 0.f, 0.f};
#pragma unroll
        for (int i = 0; i < 4; ++i)
#pragma unroll
            for (int j = 0; j < 4; ++j)
#pragma unroll
                for (int r = 0; r < 4; ++r) {
                    float w = __expf(s[i][j][r]) * rinv[i][r];
                    s[i][j][r] = w;
                    cs[j] += w;
                }

        __syncthreads();   // all Kt reads done -> Vt may overwrite

        // write w to WS[q][k]
#pragma unroll
        for (int i = 0; i < 4; ++i)
#pragma unroll
            for (int r = 0; r < 4; ++r) {
                f16* wrow = WS + (wm + 16 * i + 4 * kg + r) * AWP + wn + r16;
#pragma unroll
                for (int j = 0; j < 4; ++j) wrow[16 * j] = (f16)s[i][j][r];
            }

        // write V^T from prefetched regs: Vt[d][k]
#pragma unroll
        for (int jj = 0; jj < 4; ++jj) {
#pragma unroll
            for (int e = 0; e < 8; ++e)
                Vt[(sh + jj * 8 + e) * AVP + srow] = vreg[jj][e];
        }

        // col sums -> COL
#pragma unroll
        for (int j = 0; j < 4; ++j) {
            float c = cs[j];
            c += __shfl_xor(c, 16);
            c += __shfl_xor(c, 32);
            if (kg == 0) atomicAdd(&COL[kt * AKT + wn + 16 * j + r16], c);
        }

        __syncthreads();   // WS & Vt ready

        // PV
#pragma unroll
        for (int ks2 = 0; ks2 < 4; ++ks2) {
            half8 wa[2], vb[4];
#pragma unroll
            for (int p = 0; p < 2; ++p)
                wa[p] = *(const half8*)&WS[(qb + 16 * p + r16) * AWP + ks2 * 32 + kg * 8];
#pragma unroll
            for (int j = 0; j < 4; ++j)
                vb[j] = *(const half8*)&Vt[(16 * j + r16) * AVP + ks2 * 32 + kg * 8];
#pragma unroll
            for (int p = 0; p < 2; ++p)
#pragma unroll
                for (int j = 0; j < 4; ++j)
                    cacc[p][j] = __builtin_amdgcn_mfma_f32_16x16x32_f16(wa[p], vb[j], cacc[p][j], 0, 0, 0);
        }
    }

    // ---- epilogue: ctx (fp16) from accumulator fragments ----
#pragma unroll
    for (int p = 0; p < 2; ++p)
#pragma unroll
        for (int r = 0; r < 4; ++r) {
            f16* dst = ctx + (size_t)(b * Lc + l0 + qb + 16 * p + 4 * kg + r) * Ec + h * Dc + r16;
#pragma unroll
            for (int j = 0; j < 4; ++j) dst[16 * j] = (f16)cacc[p][j][r];
        }

    // ---- flush avg_attn ----
    __syncthreads();
#pragma unroll
    for (int t = 0; t < 4; ++t) {
        int m = t * 256 + tid;
        atomicAdd(&avg_out[b * Lc + m], COL[m] * (1.0f / (Hc * Lc)));
    }
}

// ---------------------------------------------------------------------------
// Stats finalize: spart[2*row] = sum(h), spart[2*row+1] = sum(h^2).
// ---------------------------------------------------------------------------
__global__ __launch_bounds__(256)
void stats_fin_kernel(const float* __restrict__ spart, float2* __restrict__ stats) {
    const int row = blockIdx.x * 256 + threadIdx.x;
    float ts = spart[2 * row];
    float tq = spart[2 * row + 1];
    float mean = ts * (1.0f / Ec);
    float var = tq * (1.0f / Ec) - mean * mean;
    stats[row] = make_float2(mean, rsqrtf(var + EPSc));
}

// ---------------------------------------------------------------------------
// Pooled output over fused h (hbuf).
// ---------------------------------------------------------------------------
__global__ __launch_bounds__(256)
void pool_kernel(const float* __restrict__ hbuf, const float2* __restrict__ stats,
                 const float* __restrict__ gamma, const float* __restrict__ beta,
                 float* __restrict__ pooled) {
    const int b = blockIdx.z;
    const int f = blockIdx.y * 256 + threadIdx.x;
    const int l0 = blockIdx.x * 64;
    const float g = gamma[f];
    const float be = beta[f];
    float acc = 0.f;
    for (int l = l0; l < l0 + 64; ++l) {
        size_t idx = (size_t)(b * Lc + l) * Ec + f;
        float2 st = stats[b * Lc + l];
        acc += (hbuf[idx] - st.x) * st.y * g + be;
    }
    atomicAdd(&pooled[b * Ec + f], acc * (1.0f / Lc));
}

// ---------------------------------------------------------------------------
extern "C" void kernel_launch(void* const* d_in, const int* in_sizes, int n_in,
                              void* d_out, int out_size, void* d_ws, size_t ws_size,
                              hipStream_t stream) {
    const float* x      = (const float*)d_in[0];   // (B,L,E)
    const float* w_qkv  = (const float*)d_in[1];   // (3E,E)
    const float* b_qkv  = (const float*)d_in[2];   // (3E,)
    const float* w_out  = (const float*)d_in[3];   // (E,E)
    const float* b_out  = (const float*)d_in[4];   // (E,)
    const float* gamma  = (const float*)d_in[5];   // (E,)
    const float* beta   = (const float*)d_in[6];   // (E,)
    float* out = (float*)d_out;                    // pooled (B,E) then avg_attn (B,L)

    // workspace layout (f16 units first, then f32)
    f16* wsh = (f16*)d_ws;
    f16* qkv_h  = wsh;
    f16* ctx_h  = qkv_h + (size_t)25165824;
    f16* x_h    = ctx_h + (size_t)8388608;
    f16* wqkv_h = x_h + (size_t)8388608;
    f16* wout_h = wqkv_h + (size_t)3145728;
    float* hbuf  = (float*)(wout_h + (size_t)1048576);   // h = x + attn_out
    float* stats = hbuf + (size_t)8388608;               // float2[8192] = 16384 f
    float* spart = stats + (size_t)16384;                // float[2*8192]

    const int M = Bc * Lc;   // 8192

    hipMemsetAsync(d_out, 0, (size_t)out_size * sizeof(float), stream);
    hipMemsetAsync(spart, 0, (size_t)2 * M * sizeof(float), stream);

    // 0) one-time fp32 -> fp16 conversions (single fused launch)
    cvt3_kernel<<<4096, 256, 0, stream>>>(x, w_qkv, w_out, x_h, wqkv_h, wout_h);

    // 1) QKV projection -> fp16 qkv
    dim3 g1(M / 128, (3 * Ec) / 128);
    gemm_nt_h<<<g1, 256, 0, stream>>>(x_h, wqkv_h, b_qkv, nullptr, nullptr,
                                      nullptr, qkv_h, M, 3 * Ec, Ec);

    // 2) attention + avg_attn -> fp16 ctx  (grid = (h, qt, b) for XCD locality)
    dim3 g2(Hc, Lc / AQT, Bc);
    attn_kernel<<<g2, 256, 0, stream>>>(qkv_h, ctx_h, out + Bc * Ec);

    // 3) output projection + residual + LN partial sums -> fp32 hbuf
    dim3 g3(M / 128, Ec / 128);
    gemm_nt_h<<<g3, 256, 0, stream>>>(ctx_h, wout_h, b_out, x, spart,
                                      hbuf, nullptr, M, Ec, Ec);

    // 4) LN stats finalize
    stats_fin_kernel<<<M / 256, 256, 0, stream>>>(spart, (float2*)stats);

    // 5) pooled over hbuf
    dim3 g5(16, 4, Bc);
    pool_kernel<<<g5, 256, 0, stream>>>(hbuf, (float2*)stats, gamma, beta, out);
}

// Round 17
// 317.667 us; speedup vs baseline: 1.0028x; 1.0028x over previous
//
#include <hip/hip_runtime.h>
#include <math.h>

// Problem constants (B,L,E,H,D) = (8,1024,1024,16,64)
constexpr int Bc = 8;
constexpr int Lc = 1024;
constexpr int Ec = 1024;
constexpr int Hc = 16;
constexpr int Dc = 64;
constexpr float EPSc = 1e-5f;

// ---- fp16 types ----
typedef _Float16 f16;
typedef f16 half8 __attribute__((ext_vector_type(8)));
typedef float floatx4 __attribute__((ext_vector_type(4)));

// async global->LDS 16B
static __device__ inline void gload_lds16(const f16* g, f16* l) {
    __builtin_amdgcn_global_load_lds(
        (const __attribute__((address_space(1))) void*)g,
        (__attribute__((address_space(3))) void*)l, 16, 0, 0);
}

// ---------------------------------------------------------------------------
// Fused fp32 -> fp16 conversion for x, w_qkv, w_out in ONE launch.
// ---------------------------------------------------------------------------
static __device__ inline void cvt_body(const float* __restrict__ src,
                                       f16* __restrict__ dst, int n8,
                                       int blk, int nblk) {
    int i = blk * 256 + threadIdx.x;
    const int stride = nblk * 256;
    for (; i < n8; i += stride) {
        float4 a = *(const float4*)(src + (size_t)i * 8);
        float4 b = *(const float4*)(src + (size_t)i * 8 + 4);
        half8 p;
        p[0] = (f16)a.x; p[1] = (f16)a.y; p[2] = (f16)a.z; p[3] = (f16)a.w;
        p[4] = (f16)b.x; p[5] = (f16)b.y; p[6] = (f16)b.z; p[7] = (f16)b.w;
        *(half8*)(dst + (size_t)i * 8) = p;
    }
}

__global__ __launch_bounds__(256)
void cvt3_kernel(const float* __restrict__ x, const float* __restrict__ wq,
                 const float* __restrict__ wo, f16* __restrict__ xh,
                 f16* __restrict__ wqh, f16* __restrict__ woh) {
    const int b = blockIdx.x;
    if (b < 2048)       cvt_body(x,  xh,  (Bc * Lc * Ec) / 8, b, 2048);
    else if (b < 3584)  cvt_body(wq, wqh, (3 * Ec * Ec) / 8, b - 2048, 1536);
    else                cvt_body(wo, woh, (Ec * Ec) / 8, b - 3584, 512);
}

// ---------------------------------------------------------------------------
// GEMM (R11 core): MFMA fp16 + global_load_lds, KT=64, row-major LDS +
// chunk-XOR. fp32-output path fuses residual add (h = acc+bias+resid;
// commutative -> bit-identical) and LayerNorm partial sums.
// ---------------------------------------------------------------------------
__global__ __launch_bounds__(256)
void gemm_nt_h(const f16* __restrict__ A, const f16* __restrict__ Bm,
               const float* __restrict__ bias, const float* __restrict__ resid,
               float* __restrict__ spart, float* __restrict__ Cf,
               f16* __restrict__ Ch, int M, int N, int K) {
    constexpr int TILE = 128;
    constexpr int KT = 64;
    constexpr int RSs = 64;                        // row stride in f16
    __shared__ __align__(16) f16 As[TILE * RSs];   // 16 KB
    __shared__ __align__(16) f16 Bs[TILE * RSs];   // 16 KB

    const int tid = threadIdx.x;
    const int bm = blockIdx.x * TILE;
    const int bn = blockIdx.y * TILE;

    const int wave = tid >> 6;
    const int lane = tid & 63;
    const int wm = (wave >> 1) * 64;
    const int wn = (wave & 1) * 64;
    const int r16 = lane & 15;
    const int kg = lane >> 4;
    const int kx = r16 & 7;                        // read-side XOR key (= row&7)

    floatx4 acc[4][4];
#pragma unroll
    for (int i = 0; i < 4; ++i)
#pragma unroll
        for (int j = 0; j < 4; ++j) acc[i][j] = (floatx4){0.f, 0.f, 0.f, 0.f};

    const int rbase = tid >> 3;                    // 0..31
    const int kcg = (tid & 7) ^ (rbase & 7);       // pre-swizzled global k-chunk
    const f16* apt = A + (size_t)(bm + rbase) * K + kcg * 8;
    const f16* bpt = Bm + (size_t)(bn + rbase) * K + kcg * 8;
    f16* asl = As + tid * 8;
    f16* bsl = Bs + tid * 8;

    for (int k0 = 0; k0 < K; k0 += KT) {
        __syncthreads();                           // prior ds_reads complete
#pragma unroll
        for (int q = 0; q < 4; ++q) {
            gload_lds16(apt + (size_t)(q * 32) * K + k0, asl + q * 2048);
            gload_lds16(bpt + (size_t)(q * 32) * K + k0, bsl + q * 2048);
        }
        __syncthreads();                           // vmcnt(0) drained by compiler

#pragma unroll
        for (int ks = 0; ks < 2; ++ks) {
            const int kslot = ((ks * 4 + kg) ^ kx) * 8;
            half8 af[4], bf[4];
#pragma unroll
            for (int i = 0; i < 4; ++i)
                af[i] = *(const half8*)&As[(wm + 16 * i + r16) * RSs + kslot];
#pragma unroll
            for (int j = 0; j < 4; ++j)
                bf[j] = *(const half8*)&Bs[(wn + 16 * j + r16) * RSs + kslot];
#pragma unroll
            for (int i = 0; i < 4; ++i)
#pragma unroll
                for (int j = 0; j < 4; ++j)
                    acc[i][j] = __builtin_amdgcn_mfma_f32_16x16x32_f16(af[i], bf[j], acc[i][j], 0, 0, 0);
        }
    }

    if (Ch) {
#pragma unroll
        for (int j = 0; j < 4; ++j) {
            const int col = bn + wn + 16 * j + r16;
            const float bv = bias[col];
#pragma unroll
            for (int i = 0; i < 4; ++i) {
                const int row0e = bm + wm + 16 * i + kg * 4;
#pragma unroll
                for (int r = 0; r < 4; ++r)
                    Ch[(size_t)(row0e + r) * N + col] = (f16)(acc[i][j][r] + bv);
            }
        }
    } else {
        float rsum[4][4], rsq[4][4];
#pragma unroll
        for (int i = 0; i < 4; ++i)
#pragma unroll
            for (int r = 0; r < 4; ++r) { rsum[i][r] = 0.f; rsq[i][r] = 0.f; }
#pragma unroll
        for (int j = 0; j < 4; ++j) {
            const int col = bn + wn + 16 * j + r16;
            const float bv = bias[col];
#pragma unroll
            for (int i = 0; i < 4; ++i) {
                const int row0e = bm + wm + 16 * i + kg * 4;
#pragma unroll
                for (int r = 0; r < 4; ++r) {
                    const size_t idx = (size_t)(row0e + r) * N + col;
                    float v = acc[i][j][r] + bv;
                    if (resid) v += resid[idx];
                    Cf[idx] = v;
                    rsum[i][r] += v;
                    rsq[i][r] += v * v;
                }
            }
        }
        if (spart) {
#pragma unroll
            for (int i = 0; i < 4; ++i)
#pragma unroll
                for (int r = 0; r < 4; ++r) {
                    float s = rsum[i][r], q = rsq[i][r];
                    s += __shfl_xor(s, 1); s += __shfl_xor(s, 2);
                    s += __shfl_xor(s, 4); s += __shfl_xor(s, 8);
                    q += __shfl_xor(q, 1); q += __shfl_xor(q, 2);
                    q += __shfl_xor(q, 4); q += __shfl_xor(q, 8);
                    if (r16 == 0) {
                        const int row = bm + wm + 16 * i + kg * 4 + r;
                        atomicAdd(&spart[2 * row], s);
                        atomicAdd(&spart[2 * row + 1], q);
                    }
                }
        }
    }
}

// ---------------------------------------------------------------------------
// Attention v9 (UNCHANGED): T14 prefetch + XCD-locality grid (h, qt, b).
// ---------------------------------------------------------------------------
constexpr int AQT = 128;
constexpr int AKT = 128;
constexpr int ANT = Lc / AKT;   // 8 tiles
constexpr int AKP = 72;      // f16 stride [row][d]
constexpr int AWP = 136;     // f16 stride WS [q][k]
constexpr int AVP = 136;     // f16 stride Vt [d][k]

constexpr int AQ_OFF  = 0;                   // Kq 128*72 f16 = 4608 w
constexpr int AKV_OFF = 4608;                // Kt 4608 w | Vt 64*136 f16 = 4352 w
constexpr int AW_OFF  = AKV_OFF + 4608;      // WS 128*136 f16 = 8704 w
constexpr int ARS_OFF = AW_OFF + 8704;       // RS fp32 [128]
constexpr int ACOL_OFF = ARS_OFF + 128;      // COL fp32 [1024]
constexpr int ASMEM   = ACOL_OFF + 1024;     // 19072 w = 76288 B

__global__ __launch_bounds__(256, 2)
void attn_kernel(const f16* __restrict__ qkv, f16* __restrict__ ctx,
                 float* __restrict__ avg_out) {
    __shared__ __align__(16) float smemf[ASMEM];
    f16* Kq = (f16*)(smemf + AQ_OFF);    // [q][d] (scaled by 0.125)
    f16* Kt = (f16*)(smemf + AKV_OFF);   // [k][d]
    f16* Vt = (f16*)(smemf + AKV_OFF);   // [d][k] (union)
    f16* WS = (f16*)(smemf + AW_OFF);    // [q][k]
    float* RS  = smemf + ARS_OFF;
    float* COL = smemf + ACOL_OFF;

    const int tid = threadIdx.x;
    const int h = blockIdx.x, qt = blockIdx.y, b = blockIdx.z;   // XCD = h&7
    const int l0 = qt * AQT;
    const size_t rowstride = 3 * Ec;     // f16 units
    const f16* base = qkv + (size_t)b * Lc * rowstride + (size_t)h * Dc;

    const int wave = tid >> 6, lane = tid & 63;
    const int r16 = lane & 15, kg = lane >> 4;
    const int wm = (wave >> 1) * 64;
    const int wn = (wave & 1) * 64;

    if (tid < 128) RS[tid] = 0.f;
#pragma unroll
    for (int t = 0; t < 4; ++t) COL[t * 256 + tid] = 0.f;

    const int srow = tid >> 1;
    const int sh = (tid & 1) * 32;       // f16 offset 0 or 32

    // stage Q (x 0.125, exact in f16)
    {
        const f16* src = base + (size_t)(l0 + srow) * rowstride + sh;
        f16* dst = Kq + srow * AKP + sh;
#pragma unroll
        for (int jj = 0; jj < 4; ++jj) {
            half8 p = *(const half8*)(src + jj * 8);
#pragma unroll
            for (int e = 0; e < 8; ++e) p[e] = p[e] * (f16)0.125f;
            *(half8*)(dst + jj * 8) = p;
        }
    }

    const f16* kstage = base + (size_t)srow * rowstride + Ec + sh;   // tile-0 K src
    half8 kreg[4];
#pragma unroll
    for (int jj = 0; jj < 4; ++jj) kreg[jj] = *(const half8*)(kstage + jj * 8);

    // ================= sweep 1: row sums of exp(scores) =================
    float rs[4][4];
#pragma unroll
    for (int i = 0; i < 4; ++i)
#pragma unroll
        for (int r = 0; r < 4; ++r) rs[i][r] = 0.f;

    for (int kt = 0; kt < ANT; ++kt) {
        __syncthreads();
        {   // write prefetched K tile to LDS
            f16* dst = Kt + srow * AKP + sh;
#pragma unroll
            for (int jj = 0; jj < 4; ++jj)
                *(half8*)(dst + jj * 8) = kreg[jj];
        }
        if (kt + 1 < ANT) {   // prefetch next K tile (hides under compute)
            const f16* src = kstage + (size_t)((kt + 1) * AKT) * rowstride;
#pragma unroll
            for (int jj = 0; jj < 4; ++jj) kreg[jj] = *(const half8*)(src + jj * 8);
        }
        __syncthreads();

        floatx4 s[4][4];
#pragma unroll
        for (int i = 0; i < 4; ++i)
#pragma unroll
            for (int j = 0; j < 4; ++j) s[i][j] = (floatx4){0.f, 0.f, 0.f, 0.f};
#pragma unroll
        for (int ks = 0; ks < 2; ++ks) {
            half8 af[4], bf[4];
#pragma unroll
            for (int i = 0; i < 4; ++i)
                af[i] = *(const half8*)&Kq[(wm + 16 * i + r16) * AKP + ks * 32 + kg * 8];
#pragma unroll
            for (int j = 0; j < 4; ++j)
                bf[j] = *(const half8*)&Kt[(wn + 16 * j + r16) * AKP + ks * 32 + kg * 8];
#pragma unroll
            for (int i = 0; i < 4; ++i)
#pragma unroll
                for (int j = 0; j < 4; ++j)
                    s[i][j] = __builtin_amdgcn_mfma_f32_16x16x32_f16(af[i], bf[j], s[i][j], 0, 0, 0);
        }
#pragma unroll
        for (int i = 0; i < 4; ++i)
#pragma unroll
            for (int r = 0; r < 4; ++r)
                rs[i][r] += __expf(s[i][0][r]) + __expf(s[i][1][r]) +
                            __expf(s[i][2][r]) + __expf(s[i][3][r]);
    }

    // reload K tile 0 for sweep 2 (overlaps the RS reduction below)
#pragma unroll
    for (int jj = 0; jj < 4; ++jj) kreg[jj] = *(const half8*)(kstage + jj * 8);

#pragma unroll
    for (int i = 0; i < 4; ++i)
#pragma unroll
        for (int r = 0; r < 4; ++r) {
            float v = rs[i][r];
            v += __shfl_xor(v, 1); v += __shfl_xor(v, 2);
            v += __shfl_xor(v, 4); v += __shfl_xor(v, 8);
            rs[i][r] = v;
        }
    if (r16 == 0) {
#pragma unroll
        for (int i = 0; i < 4; ++i)
#pragma unroll
            for (int r = 0; r < 4; ++r)
                atomicAdd(&RS[wm + 16 * i + 4 * kg + r], rs[i][r]);
    }
    __syncthreads();
    if (tid < 128) RS[tid] = 1.0f / RS[tid];
    __syncthreads();

    float rinv[4][4];
#pragma unroll
    for (int i = 0; i < 4; ++i)
#pragma unroll
        for (int r = 0; r < 4; ++r) rinv[i][r] = RS[wm + 16 * i + 4 * kg + r];

    // ================= sweep 2: w -> WS, col sums, PV =================
    floatx4 cacc[2][4];
#pragma unroll
    for (int p = 0; p < 2; ++p)
#pragma unroll
        for (int j = 0; j < 4; ++j) cacc[p][j] = (floatx4){0.f, 0.f, 0.f, 0.f};
    const int qb = wave * 32;

    for (int kt = 0; kt < ANT; ++kt) {
        __syncthreads();   // prev PV reads of WS/Vt done
        {   // write prefetched K tile to LDS
            f16* dst = Kt + srow * AKP + sh;
#pragma unroll
            for (int jj = 0; jj < 4; ++jj)
                *(half8*)(dst + jj * 8) = kreg[jj];
        }
        // issue THIS tile's V loads (latency hides under QK^T)
        half8 vreg[4];
        {
            const f16* src = base + (size_t)(kt * AKT + srow) * rowstride + 2 * Ec + sh;
#pragma unroll
            for (int jj = 0; jj < 4; ++jj) vreg[jj] = *(const half8*)(src + jj * 8);
        }
        if (kt + 1 < ANT) {   // prefetch next K tile
            const f16* src = kstage + (size_t)((kt + 1) * AKT) * rowstride;
#pragma unroll
            for (int jj = 0; jj < 4; ++jj) kreg[jj] = *(const half8*)(src + jj * 8);
        }
        __syncthreads();

        floatx4 s[4][4];
#pragma unroll
        for (int i = 0; i < 4; ++i)
#pragma unroll
            for (int j = 0; j < 4; ++j) s[i][j] = (floatx4){0.f, 0.f, 0.f, 0.f};
#pragma unroll
        for (int ks = 0; ks < 2; ++ks) {
            half8 af[4], bf[4];
#pragma unroll
            for (int i = 0; i < 4; ++i)
                af[i] = *(const half8*)&Kq[(wm + 16 * i + r16) * AKP + ks * 32 + kg * 8];
#pragma unroll
            for (int j = 0; j < 4; ++j)
                bf[j] = *(const half8*)&Kt[(wn + 16 * j + r16) * AKP + ks * 32 + kg * 8];
#pragma unroll
            for (int i = 0; i < 4; ++i)
#pragma unroll
                for (int j = 0; j < 4; ++j)
                    s[i][j] = __builtin_amdgcn_mfma_f32_16x16x32_f16(af[i], bf[j], s[i][j], 0, 0, 0);
        }

        float cs[4] = {0.f, 0.f, 0.f, 0.f};
#pragma unroll
        for (int i = 0; i < 4; ++i)
#pragma unroll
            for (int j = 0; j < 4; ++j)
#pragma unroll
                for (int r = 0; r < 4; ++r) {
                    float w = __expf(s[i][j][r]) * rinv[i][r];
                    s[i][j][r] = w;
                    cs[j] += w;
                }

        __syncthreads();   // all Kt reads done -> Vt may overwrite

        // write w to WS[q][k]
#pragma unroll
        for (int i = 0; i < 4; ++i)
#pragma unroll
            for (int r = 0; r < 4; ++r) {
                f16* wrow = WS + (wm + 16 * i + 4 * kg + r) * AWP + wn + r16;
#pragma unroll
                for (int j = 0; j < 4; ++j) wrow[16 * j] = (f16)s[i][j][r];
            }

        // write V^T from prefetched regs: Vt[d][k]
#pragma unroll
        for (int jj = 0; jj < 4; ++jj) {
#pragma unroll
            for (int e = 0; e < 8; ++e)
                Vt[(sh + jj * 8 + e) * AVP + srow] = vreg[jj][e];
        }

        // col sums -> COL
#pragma unroll
        for (int j = 0; j < 4; ++j) {
            float c = cs[j];
            c += __shfl_xor(c, 16);
            c += __shfl_xor(c, 32);
            if (kg == 0) atomicAdd(&COL[kt * AKT + wn + 16 * j + r16], c);
        }

        __syncthreads();   // WS & Vt ready

        // PV
#pragma unroll
        for (int ks2 = 0; ks2 < 4; ++ks2) {
            half8 wa[2], vb[4];
#pragma unroll
            for (int p = 0; p < 2; ++p)
                wa[p] = *(const half8*)&WS[(qb + 16 * p + r16) * AWP + ks2 * 32 + kg * 8];
#pragma unroll
            for (int j = 0; j < 4; ++j)
                vb[j] = *(const half8*)&Vt[(16 * j + r16) * AVP + ks2 * 32 + kg * 8];
#pragma unroll
            for (int p = 0; p < 2; ++p)
#pragma unroll
                for (int j = 0; j < 4; ++j)
                    cacc[p][j] = __builtin_amdgcn_mfma_f32_16x16x32_f16(wa[p], vb[j], cacc[p][j], 0, 0, 0);
        }
    }

    // ---- epilogue: ctx (fp16) from accumulator fragments ----
#pragma unroll
    for (int p = 0; p < 2; ++p)
#pragma unroll
        for (int r = 0; r < 4; ++r) {
            f16* dst = ctx + (size_t)(b * Lc + l0 + qb + 16 * p + 4 * kg + r) * Ec + h * Dc + r16;
#pragma unroll
            for (int j = 0; j < 4; ++j) dst[16 * j] = (f16)cacc[p][j][r];
        }

    // ---- flush avg_attn ----
    __syncthreads();
#pragma unroll
    for (int t = 0; t < 4; ++t) {
        int m = t * 256 + tid;
        atomicAdd(&avg_out[b * Lc + m], COL[m] * (1.0f / (Hc * Lc)));
    }
}

// ---------------------------------------------------------------------------
// Stats finalize: spart[2*row] = sum(h), spart[2*row+1] = sum(h^2).
// ---------------------------------------------------------------------------
__global__ __launch_bounds__(256)
void stats_fin_kernel(const float* __restrict__ spart, float2* __restrict__ stats) {
    const int row = blockIdx.x * 256 + threadIdx.x;
    float ts = spart[2 * row];
    float tq = spart[2 * row + 1];
    float mean = ts * (1.0f / Ec);
    float var = tq * (1.0f / Ec) - mean * mean;
    stats[row] = make_float2(mean, rsqrtf(var + EPSc));
}

// ---------------------------------------------------------------------------
// Pooled output over fused h (hbuf).
// ---------------------------------------------------------------------------
__global__ __launch_bounds__(256)
void pool_kernel(const float* __restrict__ hbuf, const float2* __restrict__ stats,
                 const float* __restrict__ gamma, const float* __restrict__ beta,
                 float* __restrict__ pooled) {
    const int b = blockIdx.z;
    const int f = blockIdx.y * 256 + threadIdx.x;
    const int l0 = blockIdx.x * 64;
    const float g = gamma[f];
    const float be = beta[f];
    float acc = 0.f;
    for (int l = l0; l < l0 + 64; ++l) {
        size_t idx = (size_t)(b * Lc + l) * Ec + f;
        float2 st = stats[b * Lc + l];
        acc += (hbuf[idx] - st.x) * st.y * g + be;
    }
    atomicAdd(&pooled[b * Ec + f], acc * (1.0f / Lc));
}

// ---------------------------------------------------------------------------
extern "C" void kernel_launch(void* const* d_in, const int* in_sizes, int n_in,
                              void* d_out, int out_size, void* d_ws, size_t ws_size,
                              hipStream_t stream) {
    const float* x      = (const float*)d_in[0];   // (B,L,E)
    const float* w_qkv  = (const float*)d_in[1];   // (3E,E)
    const float* b_qkv  = (const float*)d_in[2];   // (3E,)
    const float* w_out  = (const float*)d_in[3];   // (E,E)
    const float* b_out  = (const float*)d_in[4];   // (E,)
    const float* gamma  = (const float*)d_in[5];   // (E,)
    const float* beta   = (const float*)d_in[6];   // (E,)
    float* out = (float*)d_out;                    // pooled (B,E) then avg_attn (B,L)

    // workspace layout (f16 units first, then f32)
    f16* wsh = (f16*)d_ws;
    f16* qkv_h  = wsh;
    f16* ctx_h  = qkv_h + (size_t)25165824;
    f16* x_h    = ctx_h + (size_t)8388608;
    f16* wqkv_h = x_h + (size_t)8388608;
    f16* wout_h = wqkv_h + (size_t)3145728;
    float* hbuf  = (float*)(wout_h + (size_t)1048576);   // h = x + attn_out
    float* stats = hbuf + (size_t)8388608;               // float2[8192] = 16384 f
    float* spart = stats + (size_t)16384;                // float[2*8192]

    const int M = Bc * Lc;   // 8192

    hipMemsetAsync(d_out, 0, (size_t)out_size * sizeof(float), stream);
    hipMemsetAsync(spart, 0, (size_t)2 * M * sizeof(float), stream);

    // 0) one-time fp32 -> fp16 conversions (single fused launch)
    cvt3_kernel<<<4096, 256, 0, stream>>>(x, w_qkv, w_out, x_h, wqkv_h, wout_h);

    // 1) QKV projection -> fp16 qkv
    dim3 g1(M / 128, (3 * Ec) / 128);
    gemm_nt_h<<<g1, 256, 0, stream>>>(x_h, wqkv_h, b_qkv, nullptr, nullptr,
                                      nullptr, qkv_h, M, 3 * Ec, Ec);

    // 2) attention + avg_attn -> fp16 ctx  (grid = (h, qt, b) for XCD locality)
    dim3 g2(Hc, Lc / AQT, Bc);
    attn_kernel<<<g2, 256, 0, stream>>>(qkv_h, ctx_h, out + Bc * Ec);

    // 3) output projection + residual + LN partial sums -> fp32 hbuf
    dim3 g3(M / 128, Ec / 128);
    gemm_nt_h<<<g3, 256, 0, stream>>>(ctx_h, wout_h, b_out, x, spart,
                                      hbuf, nullptr, M, Ec, Ec);

    // 4) LN stats finalize
    stats_fin_kernel<<<M / 256, 256, 0, stream>>>(spart, (float2*)stats);

    // 5) pooled over hbuf
    dim3 g5(16, 4, Bc);
    pool_kernel<<<g5, 256, 0, stream>>>(hbuf, (float2*)stats, gamma, beta, out);
}

// Round 18
// 309.641 us; speedup vs baseline: 1.0287x; 1.0259x over previous
//
#include <hip/hip_runtime.h>
#include <math.h>

// Problem constants (B,L,E,H,D) = (8,1024,1024,16,64)
constexpr int Bc = 8;
constexpr int Lc = 1024;
constexpr int Ec = 1024;
constexpr int Hc = 16;
constexpr int Dc = 64;
constexpr float EPSc = 1e-5f;

// ---- fp16 types ----
typedef _Float16 f16;
typedef f16 half8 __attribute__((ext_vector_type(8)));
typedef float floatx4 __attribute__((ext_vector_type(4)));

// async global->LDS 16B
static __device__ inline void gload_lds16(const f16* g, f16* l) {
    __builtin_amdgcn_global_load_lds(
        (const __attribute__((address_space(1))) void*)g,
        (__attribute__((address_space(3))) void*)l, 16, 0, 0);
}

// ---------------------------------------------------------------------------
// Fused fp32 -> fp16 conversion for x, w_qkv, w_out in ONE launch.
// ---------------------------------------------------------------------------
static __device__ inline void cvt_body(const float* __restrict__ src,
                                       f16* __restrict__ dst, int n8,
                                       int blk, int nblk) {
    int i = blk * 256 + threadIdx.x;
    const int stride = nblk * 256;
    for (; i < n8; i += stride) {
        float4 a = *(const float4*)(src + (size_t)i * 8);
        float4 b = *(const float4*)(src + (size_t)i * 8 + 4);
        half8 p;
        p[0] = (f16)a.x; p[1] = (f16)a.y; p[2] = (f16)a.z; p[3] = (f16)a.w;
        p[4] = (f16)b.x; p[5] = (f16)b.y; p[6] = (f16)b.z; p[7] = (f16)b.w;
        *(half8*)(dst + (size_t)i * 8) = p;
    }
}

__global__ __launch_bounds__(256)
void cvt3_kernel(const float* __restrict__ x, const float* __restrict__ wq,
                 const float* __restrict__ wo, f16* __restrict__ xh,
                 f16* __restrict__ wqh, f16* __restrict__ woh) {
    const int b = blockIdx.x;
    if (b < 2048)       cvt_body(x,  xh,  (Bc * Lc * Ec) / 8, b, 2048);
    else if (b < 3584)  cvt_body(wq, wqh, (3 * Ec * Ec) / 8, b - 2048, 1536);
    else                cvt_body(wo, woh, (Ec * Ec) / 8, b - 3584, 512);
}

// ---------------------------------------------------------------------------
// GEMM (R11 core): MFMA fp16 + global_load_lds, KT=64, row-major LDS +
// chunk-XOR swizzle (both-sides).
// ---------------------------------------------------------------------------
__global__ __launch_bounds__(256)
void gemm_nt_h(const f16* __restrict__ A, const f16* __restrict__ Bm,
               const float* __restrict__ bias, float* __restrict__ Cf,
               f16* __restrict__ Ch, int M, int N, int K) {
    constexpr int TILE = 128;
    constexpr int KT = 64;
    constexpr int RSs = 64;                        // row stride in f16
    __shared__ __align__(16) f16 As[TILE * RSs];   // 16 KB
    __shared__ __align__(16) f16 Bs[TILE * RSs];   // 16 KB

    const int tid = threadIdx.x;
    const int bm = blockIdx.x * TILE;
    const int bn = blockIdx.y * TILE;

    const int wave = tid >> 6;
    const int lane = tid & 63;
    const int wm = (wave >> 1) * 64;
    const int wn = (wave & 1) * 64;
    const int r16 = lane & 15;
    const int kg = lane >> 4;
    const int kx = r16 & 7;                        // read-side XOR key (= row&7)

    floatx4 acc[4][4];
#pragma unroll
    for (int i = 0; i < 4; ++i)
#pragma unroll
        for (int j = 0; j < 4; ++j) acc[i][j] = (floatx4){0.f, 0.f, 0.f, 0.f};

    const int rbase = tid >> 3;                    // 0..31
    const int kcg = (tid & 7) ^ (rbase & 7);       // pre-swizzled global k-chunk
    const f16* apt = A + (size_t)(bm + rbase) * K + kcg * 8;
    const f16* bpt = Bm + (size_t)(bn + rbase) * K + kcg * 8;
    f16* asl = As + tid * 8;
    f16* bsl = Bs + tid * 8;

    for (int k0 = 0; k0 < K; k0 += KT) {
        __syncthreads();                           // prior ds_reads complete
#pragma unroll
        for (int q = 0; q < 4; ++q) {
            gload_lds16(apt + (size_t)(q * 32) * K + k0, asl + q * 2048);
            gload_lds16(bpt + (size_t)(q * 32) * K + k0, bsl + q * 2048);
        }
        __syncthreads();                           // vmcnt(0) drained by compiler

#pragma unroll
        for (int ks = 0; ks < 2; ++ks) {
            const int kslot = ((ks * 4 + kg) ^ kx) * 8;
            half8 af[4], bf[4];
#pragma unroll
            for (int i = 0; i < 4; ++i)
                af[i] = *(const half8*)&As[(wm + 16 * i + r16) * RSs + kslot];
#pragma unroll
            for (int j = 0; j < 4; ++j)
                bf[j] = *(const half8*)&Bs[(wn + 16 * j + r16) * RSs + kslot];
#pragma unroll
            for (int i = 0; i < 4; ++i)
#pragma unroll
                for (int j = 0; j < 4; ++j)
                    acc[i][j] = __builtin_amdgcn_mfma_f32_16x16x32_f16(af[i], bf[j], acc[i][j], 0, 0, 0);
        }
    }

    if (Ch) {
#pragma unroll
        for (int j = 0; j < 4; ++j) {
            const int col = bn + wn + 16 * j + r16;
            const float bv = bias[col];
#pragma unroll
            for (int i = 0; i < 4; ++i) {
                const int row0e = bm + wm + 16 * i + kg * 4;
#pragma unroll
                for (int r = 0; r < 4; ++r)
                    Ch[(size_t)(row0e + r) * N + col] = (f16)(acc[i][j][r] + bv);
            }
        }
    } else {
#pragma unroll
        for (int j = 0; j < 4; ++j) {
            const int col = bn + wn + 16 * j + r16;
            const float bv = bias[col];
#pragma unroll
            for (int i = 0; i < 4; ++i) {
                const int row0e = bm + wm + 16 * i + kg * 4;
#pragma unroll
                for (int r = 0; r < 4; ++r)
                    Cf[(size_t)(row0e + r) * N + col] = acc[i][j][r] + bv;
            }
        }
    }
}

// ---------------------------------------------------------------------------
// Attention v9: T14 prefetch + XCD-locality grid (h, qt, b).
// ---------------------------------------------------------------------------
constexpr int AQT = 128;
constexpr int AKT = 128;
constexpr int ANT = Lc / AKT;   // 8 tiles
constexpr int AKP = 72;      // f16 stride [row][d]
constexpr int AWP = 136;     // f16 stride WS [q][k]
constexpr int AVP = 136;     // f16 stride Vt [d][k]

constexpr int AQ_OFF  = 0;                   // Kq 128*72 f16 = 4608 w
constexpr int AKV_OFF = 4608;                // Kt 4608 w | Vt 64*136 f16 = 4352 w
constexpr int AW_OFF  = AKV_OFF + 4608;      // WS 128*136 f16 = 8704 w
constexpr int ARS_OFF = AW_OFF + 8704;       // RS fp32 [128]
constexpr int ACOL_OFF = ARS_OFF + 128;      // COL fp32 [1024]
constexpr int ASMEM   = ACOL_OFF + 1024;     // 19072 w = 76288 B

__global__ __launch_bounds__(256, 2)
void attn_kernel(const f16* __restrict__ qkv, f16* __restrict__ ctx,
                 float* __restrict__ avg_out) {
    __shared__ __align__(16) float smemf[ASMEM];
    f16* Kq = (f16*)(smemf + AQ_OFF);    // [q][d] (scaled by 0.125)
    f16* Kt = (f16*)(smemf + AKV_OFF);   // [k][d]
    f16* Vt = (f16*)(smemf + AKV_OFF);   // [d][k] (union)
    f16* WS = (f16*)(smemf + AW_OFF);    // [q][k]
    float* RS  = smemf + ARS_OFF;
    float* COL = smemf + ACOL_OFF;

    const int tid = threadIdx.x;
    const int h = blockIdx.x, qt = blockIdx.y, b = blockIdx.z;   // XCD = h&7
    const int l0 = qt * AQT;
    const size_t rowstride = 3 * Ec;     // f16 units
    const f16* base = qkv + (size_t)b * Lc * rowstride + (size_t)h * Dc;

    const int wave = tid >> 6, lane = tid & 63;
    const int r16 = lane & 15, kg = lane >> 4;
    const int wm = (wave >> 1) * 64;
    const int wn = (wave & 1) * 64;

    if (tid < 128) RS[tid] = 0.f;
#pragma unroll
    for (int t = 0; t < 4; ++t) COL[t * 256 + tid] = 0.f;

    const int srow = tid >> 1;
    const int sh = (tid & 1) * 32;       // f16 offset 0 or 32

    // stage Q (x 0.125, exact in f16)
    {
        const f16* src = base + (size_t)(l0 + srow) * rowstride + sh;
        f16* dst = Kq + srow * AKP + sh;
#pragma unroll
        for (int jj = 0; jj < 4; ++jj) {
            half8 p = *(const half8*)(src + jj * 8);
#pragma unroll
            for (int e = 0; e < 8; ++e) p[e] = p[e] * (f16)0.125f;
            *(half8*)(dst + jj * 8) = p;
        }
    }

    const f16* kstage = base + (size_t)srow * rowstride + Ec + sh;   // tile-0 K src
    half8 kreg[4];
#pragma unroll
    for (int jj = 0; jj < 4; ++jj) kreg[jj] = *(const half8*)(kstage + jj * 8);

    // ================= sweep 1: row sums of exp(scores) =================
    float rs[4][4];
#pragma unroll
    for (int i = 0; i < 4; ++i)
#pragma unroll
        for (int r = 0; r < 4; ++r) rs[i][r] = 0.f;

    for (int kt = 0; kt < ANT; ++kt) {
        __syncthreads();
        {   // write prefetched K tile to LDS
            f16* dst = Kt + srow * AKP + sh;
#pragma unroll
            for (int jj = 0; jj < 4; ++jj)
                *(half8*)(dst + jj * 8) = kreg[jj];
        }
        if (kt + 1 < ANT) {   // prefetch next K tile (hides under compute)
            const f16* src = kstage + (size_t)((kt + 1) * AKT) * rowstride;
#pragma unroll
            for (int jj = 0; jj < 4; ++jj) kreg[jj] = *(const half8*)(src + jj * 8);
        }
        __syncthreads();

        floatx4 s[4][4];
#pragma unroll
        for (int i = 0; i < 4; ++i)
#pragma unroll
            for (int j = 0; j < 4; ++j) s[i][j] = (floatx4){0.f, 0.f, 0.f, 0.f};
#pragma unroll
        for (int ks = 0; ks < 2; ++ks) {
            half8 af[4], bf[4];
#pragma unroll
            for (int i = 0; i < 4; ++i)
                af[i] = *(const half8*)&Kq[(wm + 16 * i + r16) * AKP + ks * 32 + kg * 8];
#pragma unroll
            for (int j = 0; j < 4; ++j)
                bf[j] = *(const half8*)&Kt[(wn + 16 * j + r16) * AKP + ks * 32 + kg * 8];
#pragma unroll
            for (int i = 0; i < 4; ++i)
#pragma unroll
                for (int j = 0; j < 4; ++j)
                    s[i][j] = __builtin_amdgcn_mfma_f32_16x16x32_f16(af[i], bf[j], s[i][j], 0, 0, 0);
        }
#pragma unroll
        for (int i = 0; i < 4; ++i)
#pragma unroll
            for (int r = 0; r < 4; ++r)
                rs[i][r] += __expf(s[i][0][r]) + __expf(s[i][1][r]) +
                            __expf(s[i][2][r]) + __expf(s[i][3][r]);
    }

    // reload K tile 0 for sweep 2 (overlaps the RS reduction below)
#pragma unroll
    for (int jj = 0; jj < 4; ++jj) kreg[jj] = *(const half8*)(kstage + jj * 8);

#pragma unroll
    for (int i = 0; i < 4; ++i)
#pragma unroll
        for (int r = 0; r < 4; ++r) {
            float v = rs[i][r];
            v += __shfl_xor(v, 1); v += __shfl_xor(v, 2);
            v += __shfl_xor(v, 4); v += __shfl_xor(v, 8);
            rs[i][r] = v;
        }
    if (r16 == 0) {
#pragma unroll
        for (int i = 0; i < 4; ++i)
#pragma unroll
            for (int r = 0; r < 4; ++r)
                atomicAdd(&RS[wm + 16 * i + 4 * kg + r], rs[i][r]);
    }
    __syncthreads();
    if (tid < 128) RS[tid] = 1.0f / RS[tid];
    __syncthreads();

    float rinv[4][4];
#pragma unroll
    for (int i = 0; i < 4; ++i)
#pragma unroll
        for (int r = 0; r < 4; ++r) rinv[i][r] = RS[wm + 16 * i + 4 * kg + r];

    // ================= sweep 2: w -> WS, col sums, PV =================
    floatx4 cacc[2][4];
#pragma unroll
    for (int p = 0; p < 2; ++p)
#pragma unroll
        for (int j = 0; j < 4; ++j) cacc[p][j] = (floatx4){0.f, 0.f, 0.f, 0.f};
    const int qb = wave * 32;

    for (int kt = 0; kt < ANT; ++kt) {
        __syncthreads();   // prev PV reads of WS/Vt done
        {   // write prefetched K tile to LDS
            f16* dst = Kt + srow * AKP + sh;
#pragma unroll
            for (int jj = 0; jj < 4; ++jj)
                *(half8*)(dst + jj * 8) = kreg[jj];
        }
        // issue THIS tile's V loads (latency hides under QK^T)
        half8 vreg[4];
        {
            const f16* src = base + (size_t)(kt * AKT + srow) * rowstride + 2 * Ec + sh;
#pragma unroll
            for (int jj = 0; jj < 4; ++jj) vreg[jj] = *(const half8*)(src + jj * 8);
        }
        if (kt + 1 < ANT) {   // prefetch next K tile
            const f16* src = kstage + (size_t)((kt + 1) * AKT) * rowstride;
#pragma unroll
            for (int jj = 0; jj < 4; ++jj) kreg[jj] = *(const half8*)(src + jj * 8);
        }
        __syncthreads();

        floatx4 s[4][4];
#pragma unroll
        for (int i = 0; i < 4; ++i)
#pragma unroll
            for (int j = 0; j < 4; ++j) s[i][j] = (floatx4){0.f, 0.f, 0.f, 0.f};
#pragma unroll
        for (int ks = 0; ks < 2; ++ks) {
            half8 af[4], bf[4];
#pragma unroll
            for (int i = 0; i < 4; ++i)
                af[i] = *(const half8*)&Kq[(wm + 16 * i + r16) * AKP + ks * 32 + kg * 8];
#pragma unroll
            for (int j = 0; j < 4; ++j)
                bf[j] = *(const half8*)&Kt[(wn + 16 * j + r16) * AKP + ks * 32 + kg * 8];
#pragma unroll
            for (int i = 0; i < 4; ++i)
#pragma unroll
                for (int j = 0; j < 4; ++j)
                    s[i][j] = __builtin_amdgcn_mfma_f32_16x16x32_f16(af[i], bf[j], s[i][j], 0, 0, 0);
        }

        float cs[4] = {0.f, 0.f, 0.f, 0.f};
#pragma unroll
        for (int i = 0; i < 4; ++i)
#pragma unroll
            for (int j = 0; j < 4; ++j)
#pragma unroll
                for (int r = 0; r < 4; ++r) {
                    float w = __expf(s[i][j][r]) * rinv[i][r];
                    s[i][j][r] = w;
                    cs[j] += w;
                }

        __syncthreads();   // all Kt reads done -> Vt may overwrite

        // write w to WS[q][k]
#pragma unroll
        for (int i = 0; i < 4; ++i)
#pragma unroll
            for (int r = 0; r < 4; ++r) {
                f16* wrow = WS + (wm + 16 * i + 4 * kg + r) * AWP + wn + r16;
#pragma unroll
                for (int j = 0; j < 4; ++j) wrow[16 * j] = (f16)s[i][j][r];
            }

        // write V^T from prefetched regs: Vt[d][k]
#pragma unroll
        for (int jj = 0; jj < 4; ++jj) {
#pragma unroll
            for (int e = 0; e < 8; ++e)
                Vt[(sh + jj * 8 + e) * AVP + srow] = vreg[jj][e];
        }

        // col sums -> COL
#pragma unroll
        for (int j = 0; j < 4; ++j) {
            float c = cs[j];
            c += __shfl_xor(c, 16);
            c += __shfl_xor(c, 32);
            if (kg == 0) atomicAdd(&COL[kt * AKT + wn + 16 * j + r16], c);
        }

        __syncthreads();   // WS & Vt ready

        // PV
#pragma unroll
        for (int ks2 = 0; ks2 < 4; ++ks2) {
            half8 wa[2], vb[4];
#pragma unroll
            for (int p = 0; p < 2; ++p)
                wa[p] = *(const half8*)&WS[(qb + 16 * p + r16) * AWP + ks2 * 32 + kg * 8];
#pragma unroll
            for (int j = 0; j < 4; ++j)
                vb[j] = *(const half8*)&Vt[(16 * j + r16) * AVP + ks2 * 32 + kg * 8];
#pragma unroll
            for (int p = 0; p < 2; ++p)
#pragma unroll
                for (int j = 0; j < 4; ++j)
                    cacc[p][j] = __builtin_amdgcn_mfma_f32_16x16x32_f16(wa[p], vb[j], cacc[p][j], 0, 0, 0);
        }
    }

    // ---- epilogue: ctx (fp16) from accumulator fragments ----
#pragma unroll
    for (int p = 0; p < 2; ++p)
#pragma unroll
        for (int r = 0; r < 4; ++r) {
            f16* dst = ctx + (size_t)(b * Lc + l0 + qb + 16 * p + 4 * kg + r) * Ec + h * Dc + r16;
#pragma unroll
            for (int j = 0; j < 4; ++j) dst[16 * j] = (f16)cacc[p][j][r];
        }

    // ---- flush avg_attn ----
    __syncthreads();
#pragma unroll
    for (int t = 0; t < 4; ++t) {
        int m = t * 256 + tid;
        atomicAdd(&avg_out[b * Lc + m], COL[m] * (1.0f / (Hc * Lc)));
    }
}

// ---------------------------------------------------------------------------
// LayerNorm stats: one block per (b,l) row. h = x + attn_out.
// ---------------------------------------------------------------------------
__global__ __launch_bounds__(256)
void stats_kernel(const float* __restrict__ x, const float* __restrict__ attn_out,
                  float2* __restrict__ stats) {
    const int row = blockIdx.x;
    const int tid = threadIdx.x;
    const float* xp = x + (size_t)row * Ec;
    const float* ap = attn_out + (size_t)row * Ec;
    float4 xv = *(const float4*)(xp + tid * 4);
    float4 av = *(const float4*)(ap + tid * 4);
    float h0 = xv.x + av.x, h1 = xv.y + av.y, h2 = xv.z + av.z, h3 = xv.w + av.w;
    float s = h0 + h1 + h2 + h3;
    float ss = h0 * h0 + h1 * h1 + h2 * h2 + h3 * h3;
#pragma unroll
    for (int off = 32; off; off >>= 1) {
        s += __shfl_xor(s, off);
        ss += __shfl_xor(ss, off);
    }
    __shared__ float wsum[4], wsq[4];
    const int wave = tid >> 6, lane = tid & 63;
    if (lane == 0) { wsum[wave] = s; wsq[wave] = ss; }
    __syncthreads();
    if (tid == 0) {
        float ts = wsum[0] + wsum[1] + wsum[2] + wsum[3];
        float tq = wsq[0] + wsq[1] + wsq[2] + wsq[3];
        float mean = ts * (1.0f / Ec);
        float var = tq * (1.0f / Ec) - mean * mean;
        stats[row] = make_float2(mean, rsqrtf(var + EPSc));
    }
}

// ---------------------------------------------------------------------------
// Pooled output
// ---------------------------------------------------------------------------
__global__ __launch_bounds__(256)
void pool_kernel(const float* __restrict__ x, const float* __restrict__ attn_out,
                 const float2* __restrict__ stats, const float* __restrict__ gamma,
                 const float* __restrict__ beta, float* __restrict__ pooled) {
    const int b = blockIdx.z;
    const int f = blockIdx.y * 256 + threadIdx.x;
    const int l0 = blockIdx.x * 64;
    const float g = gamma[f];
    const float be = beta[f];
    float acc = 0.f;
    for (int l = l0; l < l0 + 64; ++l) {
        size_t idx = (size_t)(b * Lc + l) * Ec + f;
        float2 st = stats[b * Lc + l];
        float h = x[idx] + attn_out[idx];
        acc += (h - st.x) * st.y * g + be;
    }
    atomicAdd(&pooled[b * Ec + f], acc * (1.0f / Lc));
}

// ---------------------------------------------------------------------------
extern "C" void kernel_launch(void* const* d_in, const int* in_sizes, int n_in,
                              void* d_out, int out_size, void* d_ws, size_t ws_size,
                              hipStream_t stream) {
    const float* x      = (const float*)d_in[0];   // (B,L,E)
    const float* w_qkv  = (const float*)d_in[1];   // (3E,E)
    const float* b_qkv  = (const float*)d_in[2];   // (3E,)
    const float* w_out  = (const float*)d_in[3];   // (E,E)
    const float* b_out  = (const float*)d_in[4];   // (E,)
    const float* gamma  = (const float*)d_in[5];   // (E,)
    const float* beta   = (const float*)d_in[6];   // (E,)
    float* out = (float*)d_out;                    // pooled (B,E) then avg_attn (B,L)

    // workspace layout (f16 units first, then f32)
    f16* wsh = (f16*)d_ws;
    f16* qkv_h  = wsh;
    f16* ctx_h  = qkv_h + (size_t)25165824;
    f16* x_h    = ctx_h + (size_t)8388608;
    f16* wqkv_h = x_h + (size_t)8388608;
    f16* wout_h = wqkv_h + (size_t)3145728;
    float* attn_out = (float*)(wout_h + (size_t)1048576);
    float* stats = attn_out + (size_t)8388608;

    const int M = Bc * Lc;   // 8192

    hipMemsetAsync(d_out, 0, (size_t)out_size * sizeof(float), stream);

    // 0) one-time fp32 -> fp16 conversions (single fused launch)
    cvt3_kernel<<<4096, 256, 0, stream>>>(x, w_qkv, w_out, x_h, wqkv_h, wout_h);

    // 1) QKV projection -> fp16 qkv
    dim3 g1(M / 128, (3 * Ec) / 128);
    gemm_nt_h<<<g1, 256, 0, stream>>>(x_h, wqkv_h, b_qkv, nullptr, qkv_h, M, 3 * Ec, Ec);

    // 2) attention + avg_attn -> fp16 ctx  (grid = (h, qt, b) for XCD locality)
    dim3 g2(Hc, Lc / AQT, Bc);
    attn_kernel<<<g2, 256, 0, stream>>>(qkv_h, ctx_h, out + Bc * Ec);

    // 3) output projection -> fp32 attn_out
    dim3 g3(M / 128, Ec / 128);
    gemm_nt_h<<<g3, 256, 0, stream>>>(ctx_h, wout_h, b_out, attn_out, nullptr, M, Ec, Ec);

    // 4) LN stats
    stats_kernel<<<M, 256, 0, stream>>>(x, attn_out, (float2*)stats);

    // 5) pooled
    dim3 g5(16, 4, Bc);
    pool_kernel<<<g5, 256, 0, stream>>>(x, attn_out, (float2*)stats, gamma, beta, out);
}